// Round 2
// baseline (726.686 us; speedup 1.0000x reference)
//
#include <hip/hip_runtime.h>

#define NN 100000
#define NE 1600000

// ---------------------------------------------------------------- z1 = x @ W1
// x: [NN,128] f32, W1: [128,32] f32 -> z1 [NN,32] f32
// block=256: 32 nodes/iter, thread = 1 node x 4 outputs
__global__ __launch_bounds__(256) void k_lin1(const float* __restrict__ x,
                                              const float* __restrict__ W1,
                                              float* __restrict__ z1) {
    __shared__ float Ws[128 * 32];     // 16 KB
    __shared__ float xs[32][129];      // padded: node-stride 129 breaks bank aliasing
    for (int i = threadIdx.x; i < 1024; i += 256) {   // 4096 f32 = 1024 float4
        float4 w = ((const float4*)W1)[i];
        float* d = &Ws[i * 4];
        d[0] = w.x; d[1] = w.y; d[2] = w.z; d[3] = w.w;
    }
    int n_loc = threadIdx.x >> 3;          // 0..31
    int j0    = (threadIdx.x & 7) * 4;     // 0,4,..,28
    for (int base = blockIdx.x * 32; base < NN; base += gridDim.x * 32) {
        __syncthreads();
        // stage 32 rows x 128 f32 = 1024 float4, coalesced
        for (int t = threadIdx.x; t < 1024; t += 256) {
            int n = t >> 5, c = t & 31;
            float4 v = ((const float4*)(x + (size_t)(base + n) * 128))[c];
            float* d = &xs[n][c * 4];
            d[0] = v.x; d[1] = v.y; d[2] = v.z; d[3] = v.w;
        }
        __syncthreads();
        float a0 = 0.f, a1 = 0.f, a2 = 0.f, a3 = 0.f;
        #pragma unroll 8
        for (int k = 0; k < 128; k++) {
            float xv = xs[n_loc][k];
            float4 w = *(const float4*)&Ws[k * 32 + j0];
            a0 = fmaf(xv, w.x, a0); a1 = fmaf(xv, w.y, a1);
            a2 = fmaf(xv, w.z, a2); a3 = fmaf(xv, w.w, a3);
        }
        *(float4*)&z1[(size_t)(base + n_loc) * 32 + j0] = make_float4(a0, a1, a2, a3);
    }
}

// ------------------------------------------------- scatter: agg[dst] += z[src]
// 32-feat version: wave = 2 edges, lane group of 32 = one edge row (coalesced)
__global__ __launch_bounds__(256) void k_scatter32(const int* __restrict__ src,
                                                   const int* __restrict__ dst,
                                                   const float* __restrict__ z,
                                                   float* __restrict__ agg) {
    unsigned int gid = blockIdx.x * 256u + threadIdx.x;
    int e = (int)(gid >> 5);
    int f = (int)(gid & 31);
    if (e < NE) {
        int s = src[e], d = dst[e];
        unsafeAtomicAdd(&agg[(size_t)d * 32 + f], z[(size_t)s * 32 + f]);
    }
}

// 64-feat version: wave = 1 edge
__global__ __launch_bounds__(256) void k_scatter64(const int* __restrict__ src,
                                                   const int* __restrict__ dst,
                                                   const float* __restrict__ z,
                                                   float* __restrict__ agg) {
    unsigned int gid = blockIdx.x * 256u + threadIdx.x;
    int e = (int)(gid >> 6);
    int f = (int)(gid & 63);
    if (e < NE) {
        int s = src[e], d = dst[e];
        unsafeAtomicAdd(&agg[(size_t)d * 64 + f], z[(size_t)s * 64 + f]);
    }
}

// --------------- fused: t = relu(z1+agg1+b1); h = relu(t@W2+b2); z2 = h@W3
// block=256: 32 nodes/iter; thread = 2 nodes x 4 outputs
__global__ __launch_bounds__(256) void k_mid(const float* __restrict__ z1,
                                             const float* __restrict__ agg1,
                                             const float* __restrict__ b1,
                                             const float* __restrict__ W2,
                                             const float* __restrict__ b2,
                                             const float* __restrict__ W3,
                                             float* __restrict__ z2) {
    __shared__ float W2s[32 * 64];   // 8 KB
    __shared__ float W3s[64 * 64];   // 16 KB
    __shared__ float ts[32][33];
    __shared__ float hs[32 * 68];    // row stride 68: 16B-aligned, bank-spread
    __shared__ float b1s[32], b2s[64];
    for (int i = threadIdx.x; i < 512; i += 256) {
        float4 w = ((const float4*)W2)[i];
        float* d = &W2s[i * 4];
        d[0] = w.x; d[1] = w.y; d[2] = w.z; d[3] = w.w;
    }
    for (int i = threadIdx.x; i < 1024; i += 256) {
        float4 w = ((const float4*)W3)[i];
        float* d = &W3s[i * 4];
        d[0] = w.x; d[1] = w.y; d[2] = w.z; d[3] = w.w;
    }
    if (threadIdx.x < 32) b1s[threadIdx.x] = b1[threadIdx.x];
    if (threadIdx.x >= 64 && threadIdx.x < 128) b2s[threadIdx.x - 64] = b2[threadIdx.x - 64];
    int n2 = threadIdx.x >> 4;            // 0..15
    int j0 = (threadIdx.x & 15) * 4;      // 0..60
    int na = 2 * n2, nb = 2 * n2 + 1;
    for (int base = blockIdx.x * 32; base < NN; base += gridDim.x * 32) {
        __syncthreads();
        #pragma unroll
        for (int r = 0; r < 4; r++) {     // phase A: t (32x32 values)
            int idx = threadIdx.x + 256 * r;
            int n = idx >> 5, f = idx & 31;
            ts[n][f] = fmaxf(z1[(size_t)base * 32 + idx] + agg1[(size_t)base * 32 + idx] + b1s[f], 0.f);
        }
        __syncthreads();
        {   // phase B: h = relu(t@W2+b2)
            float a00=0,a01=0,a02=0,a03=0,a10=0,a11=0,a12=0,a13=0;
            #pragma unroll 8
            for (int k = 0; k < 32; k++) {
                float t0 = ts[na][k], t1 = ts[nb][k];
                float4 w = *(const float4*)&W2s[k * 64 + j0];
                a00=fmaf(t0,w.x,a00); a01=fmaf(t0,w.y,a01); a02=fmaf(t0,w.z,a02); a03=fmaf(t0,w.w,a03);
                a10=fmaf(t1,w.x,a10); a11=fmaf(t1,w.y,a11); a12=fmaf(t1,w.z,a12); a13=fmaf(t1,w.w,a13);
            }
            *(float4*)&hs[na * 68 + j0] = make_float4(fmaxf(a00+b2s[j0],0.f), fmaxf(a01+b2s[j0+1],0.f),
                                                      fmaxf(a02+b2s[j0+2],0.f), fmaxf(a03+b2s[j0+3],0.f));
            *(float4*)&hs[nb * 68 + j0] = make_float4(fmaxf(a10+b2s[j0],0.f), fmaxf(a11+b2s[j0+1],0.f),
                                                      fmaxf(a12+b2s[j0+2],0.f), fmaxf(a13+b2s[j0+3],0.f));
        }
        __syncthreads();
        {   // phase C: z2 = h@W3 (bias b3 deferred to k_final, post-aggregation)
            float a00=0,a01=0,a02=0,a03=0,a10=0,a11=0,a12=0,a13=0;
            #pragma unroll 8
            for (int k = 0; k < 64; k++) {
                float h0 = hs[na * 68 + k], h1 = hs[nb * 68 + k];
                float4 w = *(const float4*)&W3s[k * 64 + j0];
                a00=fmaf(h0,w.x,a00); a01=fmaf(h0,w.y,a01); a02=fmaf(h0,w.z,a02); a03=fmaf(h0,w.w,a03);
                a10=fmaf(h1,w.x,a10); a11=fmaf(h1,w.y,a11); a12=fmaf(h1,w.z,a12); a13=fmaf(h1,w.w,a13);
            }
            *(float4*)&z2[(size_t)(base + na) * 64 + j0] = make_float4(a00,a01,a02,a03);
            *(float4*)&z2[(size_t)(base + nb) * 64 + j0] = make_float4(a10,a11,a12,a13);
        }
    }
}

// --------- final: u = relu(z2+agg2+b3); out = relu(u@W4+b4) -> f32 + pooled
__global__ __launch_bounds__(256) void k_final(const float* __restrict__ z2,
                                               const float* __restrict__ agg2,
                                               const float* __restrict__ b3,
                                               const float* __restrict__ W4,
                                               const float* __restrict__ b4,
                                               float* __restrict__ out,
                                               float* __restrict__ gpool) {
    __shared__ float W4s[64 * 64];   // 16 KB
    __shared__ float us[32 * 68];
    __shared__ float b3s[64], b4s[64], pool[64];
    for (int i = threadIdx.x; i < 1024; i += 256) {
        float4 w = ((const float4*)W4)[i];
        float* d = &W4s[i * 4];
        d[0] = w.x; d[1] = w.y; d[2] = w.z; d[3] = w.w;
    }
    if (threadIdx.x < 64) { b3s[threadIdx.x] = b3[threadIdx.x]; pool[threadIdx.x] = 0.f; }
    if (threadIdx.x >= 64 && threadIdx.x < 128) b4s[threadIdx.x - 64] = b4[threadIdx.x - 64];
    int n2 = threadIdx.x >> 4;
    int j0 = (threadIdx.x & 15) * 4;
    int na = 2 * n2, nb = 2 * n2 + 1;
    float p0 = 0.f, p1 = 0.f, p2 = 0.f, p3 = 0.f;
    for (int base = blockIdx.x * 32; base < NN; base += gridDim.x * 32) {
        __syncthreads();
        #pragma unroll
        for (int r = 0; r < 8; r++) {     // phase A: u (32x64)
            int idx = threadIdx.x + 256 * r;
            int n = idx >> 6, f = idx & 63;
            us[n * 68 + f] = fmaxf(z2[(size_t)base * 64 + idx] + agg2[(size_t)base * 64 + idx] + b3s[f], 0.f);
        }
        __syncthreads();
        float a00=0,a01=0,a02=0,a03=0,a10=0,a11=0,a12=0,a13=0;
        #pragma unroll 8
        for (int k = 0; k < 64; k++) {
            float u0 = us[na * 68 + k], u1 = us[nb * 68 + k];
            float4 w = *(const float4*)&W4s[k * 64 + j0];
            a00=fmaf(u0,w.x,a00); a01=fmaf(u0,w.y,a01); a02=fmaf(u0,w.z,a02); a03=fmaf(u0,w.w,a03);
            a10=fmaf(u1,w.x,a10); a11=fmaf(u1,w.y,a11); a12=fmaf(u1,w.z,a12); a13=fmaf(u1,w.w,a13);
        }
        float v00=fmaxf(a00+b4s[j0],0.f), v01=fmaxf(a01+b4s[j0+1],0.f);
        float v02=fmaxf(a02+b4s[j0+2],0.f), v03=fmaxf(a03+b4s[j0+3],0.f);
        float v10=fmaxf(a10+b4s[j0],0.f), v11=fmaxf(a11+b4s[j0+1],0.f);
        float v12=fmaxf(a12+b4s[j0+2],0.f), v13=fmaxf(a13+b4s[j0+3],0.f);
        *(float4*)&out[(size_t)(base + na) * 64 + j0] = make_float4(v00, v01, v02, v03);
        *(float4*)&out[(size_t)(base + nb) * 64 + j0] = make_float4(v10, v11, v12, v13);
        p0 += v00 + v10; p1 += v01 + v11; p2 += v02 + v12; p3 += v03 + v13;
    }
    __syncthreads();
    atomicAdd(&pool[j0 + 0], p0);
    atomicAdd(&pool[j0 + 1], p1);
    atomicAdd(&pool[j0 + 2], p2);
    atomicAdd(&pool[j0 + 3], p3);
    __syncthreads();
    if (threadIdx.x < 64) unsafeAtomicAdd(&gpool[threadIdx.x], pool[threadIdx.x]);
}

__global__ void k_pool(const float* __restrict__ gpool, float* __restrict__ out) {
    int t = threadIdx.x;
    if (t < 64) out[(size_t)NN * 64 + t] = gpool[t] * (1.0f / NN);
}

extern "C" void kernel_launch(void* const* d_in, const int* in_sizes, int n_in,
                              void* d_out, int out_size, void* d_ws, size_t ws_size,
                              hipStream_t stream) {
    const float* x  = (const float*)d_in[0];
    const int*   ei = (const int*)d_in[1];
    // d_in[2] = batch (unused: reference overwrites with zeros -> single graph)
    const float* W1 = (const float*)d_in[3];
    const float* b1 = (const float*)d_in[4];
    const float* W2 = (const float*)d_in[5];
    const float* b2 = (const float*)d_in[6];
    const float* W3 = (const float*)d_in[7];
    const float* b3 = (const float*)d_in[8];
    const float* W4 = (const float*)d_in[9];
    const float* b4 = (const float*)d_in[10];
    float* out = (float*)d_out;

    // ws layout (floats). agg2 ALIASES [z1|agg1] (both dead after k_mid):
    //   [0, NN*32)        z1        / agg2 first half
    //   [NN*32, NN*64)    agg1      / agg2 second half
    //   [NN*64, NN*128)   z2
    //   [NN*128, +64)     gpool
    // total 51.2 MB + 256 B
    float* ws    = (float*)d_ws;
    float* z1    = ws;
    float* agg1  = ws + (size_t)NN * 32;
    float* agg2  = ws;                     // aliases z1+agg1 after k_mid
    float* z2    = ws + (size_t)NN * 64;
    float* gpool = ws + (size_t)NN * 128;
    const int* src = ei;
    const int* dst = ei + NE;

    hipMemsetAsync(agg1, 0, (size_t)NN * 32 * sizeof(float), stream);
    hipMemsetAsync(gpool, 0, 64 * sizeof(float), stream);
    k_lin1<<<1024, 256, 0, stream>>>(x, W1, z1);
    k_scatter32<<<NE * 32 / 256, 256, 0, stream>>>(src, dst, z1, agg1);
    k_mid<<<1024, 256, 0, stream>>>(z1, agg1, b1, W2, b2, W3, z2);
    hipMemsetAsync(agg2, 0, (size_t)NN * 64 * sizeof(float), stream);
    k_scatter64<<<NE * 64 / 256, 256, 0, stream>>>(src, dst, z2, agg2);
    k_final<<<1024, 256, 0, stream>>>(z2, agg2, b3, W4, b4, out, gpool);
    k_pool<<<1, 64, 0, stream>>>(gpool, out);
}

// Round 3
// 493.256 us; speedup vs baseline: 1.4732x; 1.4732x over previous
//
#include <hip/hip_runtime.h>

#define NN 100000
#define NE 1600000
#define NSB 98   // scan blocks: 98 * 1024 >= NN

// ================================================================ CSR build
__global__ __launch_bounds__(256) void k_count(const int* __restrict__ dst,
                                               int* __restrict__ counts) {
    int e = blockIdx.x * 256 + threadIdx.x;
    if (e < NE) atomicAdd(&counts[dst[e]], 1);
}

// hierarchical exclusive scan: A (per-block prescan + block totals)
__global__ __launch_bounds__(256) void k_scanA(const int* __restrict__ counts,
                                               int* __restrict__ pre,
                                               int* __restrict__ aux) {
    __shared__ int s[256];
    int t = threadIdx.x;
    int idx = blockIdx.x * 1024 + t * 4;
    int c0 = (idx + 0 < NN) ? counts[idx + 0] : 0;
    int c1 = (idx + 1 < NN) ? counts[idx + 1] : 0;
    int c2 = (idx + 2 < NN) ? counts[idx + 2] : 0;
    int c3 = (idx + 3 < NN) ? counts[idx + 3] : 0;
    int tsum = c0 + c1 + c2 + c3;
    s[t] = tsum;
    __syncthreads();
    for (int off = 1; off < 256; off <<= 1) {
        int v = (t >= off) ? s[t - off] : 0;
        __syncthreads();
        s[t] += v;
        __syncthreads();
    }
    int excl = s[t] - tsum;
    if (idx + 0 < NN) pre[idx + 0] = excl;
    if (idx + 1 < NN) pre[idx + 1] = excl + c0;
    if (idx + 2 < NN) pre[idx + 2] = excl + c0 + c1;
    if (idx + 3 < NN) pre[idx + 3] = excl + c0 + c1 + c2;
    if (t == 255) aux[blockIdx.x] = s[255];
}

// B: scan the 98 block totals (single block)
__global__ __launch_bounds__(128) void k_scanB(int* __restrict__ aux) {
    __shared__ int s[128];
    int t = threadIdx.x;
    int v = (t < NSB) ? aux[t] : 0;
    s[t] = v;
    __syncthreads();
    for (int off = 1; off < 128; off <<= 1) {
        int u = (t >= off) ? s[t - off] : 0;
        __syncthreads();
        s[t] += u;
        __syncthreads();
    }
    if (t < NSB) aux[t] = s[t] - v;   // exclusive
}

// C: add block offsets; write row_start (pre) and cursor copy
__global__ __launch_bounds__(256) void k_scanC(int* __restrict__ pre,
                                               const int* __restrict__ aux,
                                               int* __restrict__ cursor) {
    int idx = blockIdx.x * 1024 + threadIdx.x * 4;
    int a = aux[blockIdx.x];
    #pragma unroll
    for (int i = 0; i < 4; i++)
        if (idx + i < NN) {
            int v = pre[idx + i] + a;
            pre[idx + i] = v;
            cursor[idx + i] = v;
        }
}

// fill: place src ids grouped by dst. After this, cursor[n] == row_start[n+1].
__global__ __launch_bounds__(256) void k_fill(const int* __restrict__ src,
                                              const int* __restrict__ dst,
                                              int* __restrict__ cursor,
                                              int* __restrict__ csr) {
    int e = blockIdx.x * 256 + threadIdx.x;
    if (e < NE) {
        int p = atomicAdd(&cursor[dst[e]], 1);
        csr[p] = src[e];
    }
}

// ================================================================ gathers
// 32-feat: half-wave per node, lane = feature. csr index loads are broadcast.
__global__ __launch_bounds__(256) void k_gather32(const int* __restrict__ row,
                                                  const int* __restrict__ rend,
                                                  const int* __restrict__ csr,
                                                  const float* __restrict__ z,
                                                  float* __restrict__ agg) {
    int n = blockIdx.x * 8 + (threadIdx.x >> 5);
    int f = threadIdx.x & 31;
    int j = row[n], e = rend[n];
    float a0 = 0.f, a1 = 0.f, a2 = 0.f, a3 = 0.f;
    for (; j + 3 < e; j += 4) {
        int i0 = csr[j], i1 = csr[j + 1], i2 = csr[j + 2], i3 = csr[j + 3];
        a0 += z[(size_t)i0 * 32 + f];
        a1 += z[(size_t)i1 * 32 + f];
        a2 += z[(size_t)i2 * 32 + f];
        a3 += z[(size_t)i3 * 32 + f];
    }
    for (; j < e; j++) a0 += z[(size_t)csr[j] * 32 + f];
    agg[(size_t)n * 32 + f] = (a0 + a1) + (a2 + a3);
}

// 64-feat: full wave per node.
__global__ __launch_bounds__(256) void k_gather64(const int* __restrict__ row,
                                                  const int* __restrict__ rend,
                                                  const int* __restrict__ csr,
                                                  const float* __restrict__ z,
                                                  float* __restrict__ agg) {
    int n = blockIdx.x * 4 + (threadIdx.x >> 6);
    int f = threadIdx.x & 63;
    int j = row[n], e = rend[n];
    float a0 = 0.f, a1 = 0.f, a2 = 0.f, a3 = 0.f;
    for (; j + 3 < e; j += 4) {
        int i0 = csr[j], i1 = csr[j + 1], i2 = csr[j + 2], i3 = csr[j + 3];
        a0 += z[(size_t)i0 * 64 + f];
        a1 += z[(size_t)i1 * 64 + f];
        a2 += z[(size_t)i2 * 64 + f];
        a3 += z[(size_t)i3 * 64 + f];
    }
    for (; j < e; j++) a0 += z[(size_t)csr[j] * 64 + f];
    agg[(size_t)n * 64 + f] = (a0 + a1) + (a2 + a3);
}

// ================================================================ z1 = x @ W1
__global__ __launch_bounds__(256) void k_lin1(const float* __restrict__ x,
                                              const float* __restrict__ W1,
                                              float* __restrict__ z1) {
    __shared__ float Ws[128 * 32];
    __shared__ float xs[32][129];
    for (int i = threadIdx.x; i < 1024; i += 256) {
        float4 w = ((const float4*)W1)[i];
        float* d = &Ws[i * 4];
        d[0] = w.x; d[1] = w.y; d[2] = w.z; d[3] = w.w;
    }
    int n_loc = threadIdx.x >> 3;
    int j0    = (threadIdx.x & 7) * 4;
    for (int base = blockIdx.x * 32; base < NN; base += gridDim.x * 32) {
        __syncthreads();
        for (int t = threadIdx.x; t < 1024; t += 256) {
            int n = t >> 5, c = t & 31;
            float4 v = ((const float4*)(x + (size_t)(base + n) * 128))[c];
            float* d = &xs[n][c * 4];
            d[0] = v.x; d[1] = v.y; d[2] = v.z; d[3] = v.w;
        }
        __syncthreads();
        float a0 = 0.f, a1 = 0.f, a2 = 0.f, a3 = 0.f;
        #pragma unroll 8
        for (int k = 0; k < 128; k++) {
            float xv = xs[n_loc][k];
            float4 w = *(const float4*)&Ws[k * 32 + j0];
            a0 = fmaf(xv, w.x, a0); a1 = fmaf(xv, w.y, a1);
            a2 = fmaf(xv, w.z, a2); a3 = fmaf(xv, w.w, a3);
        }
        *(float4*)&z1[(size_t)(base + n_loc) * 32 + j0] = make_float4(a0, a1, a2, a3);
    }
}

// --------------- fused: t = relu(z1+agg1+b1); h = relu(t@W2+b2); z2 = h@W3
__global__ __launch_bounds__(256) void k_mid(const float* __restrict__ z1,
                                             const float* __restrict__ agg1,
                                             const float* __restrict__ b1,
                                             const float* __restrict__ W2,
                                             const float* __restrict__ b2,
                                             const float* __restrict__ W3,
                                             float* __restrict__ z2) {
    __shared__ float W2s[32 * 64];
    __shared__ float W3s[64 * 64];
    __shared__ float ts[32][33];
    __shared__ float hs[32 * 68];
    __shared__ float b1s[32], b2s[64];
    for (int i = threadIdx.x; i < 512; i += 256) {
        float4 w = ((const float4*)W2)[i];
        float* d = &W2s[i * 4];
        d[0] = w.x; d[1] = w.y; d[2] = w.z; d[3] = w.w;
    }
    for (int i = threadIdx.x; i < 1024; i += 256) {
        float4 w = ((const float4*)W3)[i];
        float* d = &W3s[i * 4];
        d[0] = w.x; d[1] = w.y; d[2] = w.z; d[3] = w.w;
    }
    if (threadIdx.x < 32) b1s[threadIdx.x] = b1[threadIdx.x];
    if (threadIdx.x >= 64 && threadIdx.x < 128) b2s[threadIdx.x - 64] = b2[threadIdx.x - 64];
    int n2 = threadIdx.x >> 4;
    int j0 = (threadIdx.x & 15) * 4;
    int na = 2 * n2, nb = 2 * n2 + 1;
    for (int base = blockIdx.x * 32; base < NN; base += gridDim.x * 32) {
        __syncthreads();
        #pragma unroll
        for (int r = 0; r < 4; r++) {
            int idx = threadIdx.x + 256 * r;
            int n = idx >> 5, f = idx & 31;
            ts[n][f] = fmaxf(z1[(size_t)base * 32 + idx] + agg1[(size_t)base * 32 + idx] + b1s[f], 0.f);
        }
        __syncthreads();
        {
            float a00=0,a01=0,a02=0,a03=0,a10=0,a11=0,a12=0,a13=0;
            #pragma unroll 8
            for (int k = 0; k < 32; k++) {
                float t0 = ts[na][k], t1 = ts[nb][k];
                float4 w = *(const float4*)&W2s[k * 64 + j0];
                a00=fmaf(t0,w.x,a00); a01=fmaf(t0,w.y,a01); a02=fmaf(t0,w.z,a02); a03=fmaf(t0,w.w,a03);
                a10=fmaf(t1,w.x,a10); a11=fmaf(t1,w.y,a11); a12=fmaf(t1,w.z,a12); a13=fmaf(t1,w.w,a13);
            }
            *(float4*)&hs[na * 68 + j0] = make_float4(fmaxf(a00+b2s[j0],0.f), fmaxf(a01+b2s[j0+1],0.f),
                                                      fmaxf(a02+b2s[j0+2],0.f), fmaxf(a03+b2s[j0+3],0.f));
            *(float4*)&hs[nb * 68 + j0] = make_float4(fmaxf(a10+b2s[j0],0.f), fmaxf(a11+b2s[j0+1],0.f),
                                                      fmaxf(a12+b2s[j0+2],0.f), fmaxf(a13+b2s[j0+3],0.f));
        }
        __syncthreads();
        {
            float a00=0,a01=0,a02=0,a03=0,a10=0,a11=0,a12=0,a13=0;
            #pragma unroll 8
            for (int k = 0; k < 64; k++) {
                float h0 = hs[na * 68 + k], h1 = hs[nb * 68 + k];
                float4 w = *(const float4*)&W3s[k * 64 + j0];
                a00=fmaf(h0,w.x,a00); a01=fmaf(h0,w.y,a01); a02=fmaf(h0,w.z,a02); a03=fmaf(h0,w.w,a03);
                a10=fmaf(h1,w.x,a10); a11=fmaf(h1,w.y,a11); a12=fmaf(h1,w.z,a12); a13=fmaf(h1,w.w,a13);
            }
            *(float4*)&z2[(size_t)(base + na) * 64 + j0] = make_float4(a00,a01,a02,a03);
            *(float4*)&z2[(size_t)(base + nb) * 64 + j0] = make_float4(a10,a11,a12,a13);
        }
    }
}

// --------- final: u = relu(z2+agg2+b3); out = relu(u@W4+b4) -> f32 + pooled
__global__ __launch_bounds__(256) void k_final(const float* __restrict__ z2,
                                               const float* __restrict__ agg2,
                                               const float* __restrict__ b3,
                                               const float* __restrict__ W4,
                                               const float* __restrict__ b4,
                                               float* __restrict__ out,
                                               float* __restrict__ gpool) {
    __shared__ float W4s[64 * 64];
    __shared__ float us[32 * 68];
    __shared__ float b3s[64], b4s[64], pool[64];
    for (int i = threadIdx.x; i < 1024; i += 256) {
        float4 w = ((const float4*)W4)[i];
        float* d = &W4s[i * 4];
        d[0] = w.x; d[1] = w.y; d[2] = w.z; d[3] = w.w;
    }
    if (threadIdx.x < 64) { b3s[threadIdx.x] = b3[threadIdx.x]; pool[threadIdx.x] = 0.f; }
    if (threadIdx.x >= 64 && threadIdx.x < 128) b4s[threadIdx.x - 64] = b4[threadIdx.x - 64];
    int n2 = threadIdx.x >> 4;
    int j0 = (threadIdx.x & 15) * 4;
    int na = 2 * n2, nb = 2 * n2 + 1;
    float p0 = 0.f, p1 = 0.f, p2 = 0.f, p3 = 0.f;
    for (int base = blockIdx.x * 32; base < NN; base += gridDim.x * 32) {
        __syncthreads();
        #pragma unroll
        for (int r = 0; r < 8; r++) {
            int idx = threadIdx.x + 256 * r;
            int n = idx >> 6, f = idx & 63;
            us[n * 68 + f] = fmaxf(z2[(size_t)base * 64 + idx] + agg2[(size_t)base * 64 + idx] + b3s[f], 0.f);
        }
        __syncthreads();
        float a00=0,a01=0,a02=0,a03=0,a10=0,a11=0,a12=0,a13=0;
        #pragma unroll 8
        for (int k = 0; k < 64; k++) {
            float u0 = us[na * 68 + k], u1 = us[nb * 68 + k];
            float4 w = *(const float4*)&W4s[k * 64 + j0];
            a00=fmaf(u0,w.x,a00); a01=fmaf(u0,w.y,a01); a02=fmaf(u0,w.z,a02); a03=fmaf(u0,w.w,a03);
            a10=fmaf(u1,w.x,a10); a11=fmaf(u1,w.y,a11); a12=fmaf(u1,w.z,a12); a13=fmaf(u1,w.w,a13);
        }
        float v00=fmaxf(a00+b4s[j0],0.f), v01=fmaxf(a01+b4s[j0+1],0.f);
        float v02=fmaxf(a02+b4s[j0+2],0.f), v03=fmaxf(a03+b4s[j0+3],0.f);
        float v10=fmaxf(a10+b4s[j0],0.f), v11=fmaxf(a11+b4s[j0+1],0.f);
        float v12=fmaxf(a12+b4s[j0+2],0.f), v13=fmaxf(a13+b4s[j0+3],0.f);
        *(float4*)&out[(size_t)(base + na) * 64 + j0] = make_float4(v00, v01, v02, v03);
        *(float4*)&out[(size_t)(base + nb) * 64 + j0] = make_float4(v10, v11, v12, v13);
        p0 += v00 + v10; p1 += v01 + v11; p2 += v02 + v12; p3 += v03 + v13;
    }
    __syncthreads();
    atomicAdd(&pool[j0 + 0], p0);
    atomicAdd(&pool[j0 + 1], p1);
    atomicAdd(&pool[j0 + 2], p2);
    atomicAdd(&pool[j0 + 3], p3);
    __syncthreads();
    if (threadIdx.x < 64) unsafeAtomicAdd(&gpool[threadIdx.x], pool[threadIdx.x]);
}

__global__ void k_pool(const float* __restrict__ gpool, float* __restrict__ out) {
    int t = threadIdx.x;
    if (t < 64) out[(size_t)NN * 64 + t] = gpool[t] * (1.0f / NN);
}

extern "C" void kernel_launch(void* const* d_in, const int* in_sizes, int n_in,
                              void* d_out, int out_size, void* d_ws, size_t ws_size,
                              hipStream_t stream) {
    const float* x  = (const float*)d_in[0];
    const int*   ei = (const int*)d_in[1];
    const float* W1 = (const float*)d_in[3];
    const float* b1 = (const float*)d_in[4];
    const float* W2 = (const float*)d_in[5];
    const float* b2 = (const float*)d_in[6];
    const float* W3 = (const float*)d_in[7];
    const float* b3 = (const float*)d_in[8];
    const float* W4 = (const float*)d_in[9];
    const float* b4 = (const float*)d_in[10];
    float* out = (float*)d_out;

    // ws layout (4B units):
    //   ints:  counts[NN] | row[NN] | cursor[NN] | aux[128] | csr[NE]
    //   f32:   z1[NN*32] | agg1[NN*32] | z2[NN*64] | gpool[64]
    //   agg2[NN*64] ALIASES z1+agg1 (dead after k_mid).   total ~59 MB
    int*   ip     = (int*)d_ws;
    int*   counts = ip;
    int*   row    = ip + NN;
    int*   cursor = ip + 2 * NN;
    int*   aux    = ip + 3 * NN;
    int*   csr    = ip + 3 * NN + 128;
    float* fp     = (float*)(ip + 3 * NN + 128 + NE);
    float* z1     = fp;
    float* agg1   = fp + (size_t)NN * 32;
    float* agg2   = fp;                       // alias
    float* z2     = fp + (size_t)NN * 64;
    float* gpool  = fp + (size_t)NN * 128;
    const int* src = ei;
    const int* dst = ei + NE;

    hipMemsetAsync(counts, 0, NN * sizeof(int), stream);
    hipMemsetAsync(gpool, 0, 64 * sizeof(float), stream);
    // CSR build (overlaps nothing; z1 compute is independent and long)
    k_count<<<(NE + 255) / 256, 256, 0, stream>>>(dst, counts);
    k_scanA<<<NSB, 256, 0, stream>>>(counts, row, aux);
    k_scanB<<<1, 128, 0, stream>>>(aux);
    k_scanC<<<NSB, 256, 0, stream>>>(row, aux, cursor);
    k_fill<<<(NE + 255) / 256, 256, 0, stream>>>(src, dst, cursor, csr);
    // layer 1
    k_lin1<<<1024, 256, 0, stream>>>(x, W1, z1);
    k_gather32<<<NN / 8, 256, 0, stream>>>(row, cursor, csr, z1, agg1);
    k_mid<<<1024, 256, 0, stream>>>(z1, agg1, b1, W2, b2, W3, z2);
    // layer 2
    k_gather64<<<NN / 4, 256, 0, stream>>>(row, cursor, csr, z2, agg2);
    k_final<<<1024, 256, 0, stream>>>(z2, agg2, b3, W4, b4, out, gpool);
    k_pool<<<1, 64, 0, stream>>>(gpool, out);
}

// Round 4
// 433.679 us; speedup vs baseline: 1.6756x; 1.1374x over previous
//
#include <hip/hip_runtime.h>

#define NN 100000
#define NE 1600000
#define NLB 256          // local-sort blocks
#define CHUNK (NE / NLB) // 6250 edges per block
#define NB 98            // dst buckets (dst >> 10), 98*1024 >= NN
#define BN 1024          // nodes per bucket

// ============================================ pass 1: block-local bucket sort
// Each block sorts its 6250-edge chunk by dst-bucket into a private contiguous
// region of `pairs` (single-XCD write window -> L2 write-combining).
__global__ __launch_bounds__(256) void k_lsort(const int* __restrict__ src,
                                               const int* __restrict__ dst,
                                               int2* __restrict__ pairs,
                                               int* __restrict__ tstart,
                                               int* __restrict__ tcnt,
                                               int* __restrict__ btot) {
    __shared__ int cnt[NB];
    __shared__ int sc[256];
    __shared__ int cur[NB];
    int tid = threadIdx.x, blk = blockIdx.x;
    int e0 = blk * CHUNK;
    for (int i = tid; i < NB; i += 256) cnt[i] = 0;
    __syncthreads();
    for (int i = tid; i < CHUNK; i += 256) atomicAdd(&cnt[dst[e0 + i] >> 10], 1);
    __syncthreads();
    sc[tid] = (tid < NB) ? cnt[tid] : 0;
    __syncthreads();
    for (int off = 1; off < 256; off <<= 1) {
        int v = (tid >= off) ? sc[tid - off] : 0;
        __syncthreads();
        sc[tid] += v;
        __syncthreads();
    }
    if (tid < NB) {
        int excl = sc[tid] - cnt[tid];
        cur[tid] = excl;
        tstart[blk * NB + tid] = excl;          // chunk-relative
        tcnt[blk * NB + tid]   = cnt[tid];
        atomicAdd(&btot[tid], cnt[tid]);
    }
    __syncthreads();
    for (int i = tid; i < CHUNK; i += 256) {
        int d = dst[e0 + i], s = src[e0 + i];
        int p = atomicAdd(&cur[d >> 10], 1);
        pairs[e0 + p] = make_int2(s, d);
    }
}

// ============================================ pass 2: per-bucket node CSR
// One block per bucket: gather the bucket's 256 segments, LDS count/scan over
// its 1024 nodes, place src ids node-grouped into csr; emit row/rend.
__global__ __launch_bounds__(256) void k_build(const int2* __restrict__ pairs,
                                               const int* __restrict__ tstart,
                                               const int* __restrict__ tcnt,
                                               const int* __restrict__ btot,
                                               int* __restrict__ csr,
                                               int* __restrict__ row,
                                               int* __restrict__ rend) {
    __shared__ int sc[256];
    __shared__ int segE[NLB + 1];    // exclusive prefix of segment counts
    __shared__ int segS[NLB];        // global source start of each segment
    __shared__ int ncnt[BN];         // node counts, later reused as cursors
    __shared__ int nbase[BN + 1];
    __shared__ int base_s, T_s;
    int tid = threadIdx.x, b = blockIdx.x;

    // bucket base = exclusive prefix of btot
    sc[tid] = (tid < NB) ? btot[tid] : 0;
    __syncthreads();
    for (int off = 1; off < 256; off <<= 1) {
        int v = (tid >= off) ? sc[tid - off] : 0;
        __syncthreads();
        sc[tid] += v;
        __syncthreads();
    }
    if (tid == 0) base_s = (b == 0) ? 0 : sc[b - 1];
    __syncthreads();

    // segment table (column b of tstart/tcnt)
    int mycnt = tcnt[tid * NB + b];
    segS[tid] = tid * CHUNK + tstart[tid * NB + b];
    sc[tid] = mycnt;
    __syncthreads();
    for (int off = 1; off < 256; off <<= 1) {
        int v = (tid >= off) ? sc[tid - off] : 0;
        __syncthreads();
        sc[tid] += v;
        __syncthreads();
    }
    segE[tid + 1] = sc[tid];
    if (tid == 0) segE[0] = 0;
    if (tid == 255) T_s = sc[255];
    for (int i = tid; i < BN; i += 256) ncnt[i] = 0;
    __syncthreads();
    int T = T_s, base = base_s;

    // count phase
    for (int i = tid; i < T; i += 256) {
        int lo = 0, hi = NLB;
        while (hi - lo > 1) { int mid = (lo + hi) >> 1; if (segE[mid] <= i) lo = mid; else hi = mid; }
        int2 pr = pairs[segS[lo] + (i - segE[lo])];
        atomicAdd(&ncnt[pr.y & (BN - 1)], 1);
    }
    __syncthreads();

    // scan 1024 node counts (4 per thread)
    int c0 = ncnt[4 * tid], c1 = ncnt[4 * tid + 1], c2 = ncnt[4 * tid + 2], c3 = ncnt[4 * tid + 3];
    int tsum = c0 + c1 + c2 + c3;
    sc[tid] = tsum;
    __syncthreads();
    for (int off = 1; off < 256; off <<= 1) {
        int v = (tid >= off) ? sc[tid - off] : 0;
        __syncthreads();
        sc[tid] += v;
        __syncthreads();
    }
    int excl = sc[tid] - tsum;
    nbase[4 * tid]     = excl;
    nbase[4 * tid + 1] = excl + c0;
    nbase[4 * tid + 2] = excl + c0 + c1;
    nbase[4 * tid + 3] = excl + c0 + c1 + c2;
    if (tid == 255) nbase[BN] = sc[255];
    __syncthreads();

    // emit row/rend, reset cursors
    for (int ln = tid; ln < BN; ln += 256) {
        int n = b * BN + ln;
        if (n < NN) { row[n] = base + nbase[ln]; rend[n] = base + nbase[ln + 1]; }
        ncnt[ln] = 0;
    }
    __syncthreads();

    // place phase (csr window ~65KB, single block -> single-XCD write combine)
    for (int i = tid; i < T; i += 256) {
        int lo = 0, hi = NLB;
        while (hi - lo > 1) { int mid = (lo + hi) >> 1; if (segE[mid] <= i) lo = mid; else hi = mid; }
        int2 pr = pairs[segS[lo] + (i - segE[lo])];
        int ln = pr.y & (BN - 1);
        int p = atomicAdd(&ncnt[ln], 1);
        csr[base + nbase[ln] + p] = pr.x;
    }
}

// ================================================================ gathers
__global__ __launch_bounds__(256) void k_gather32(const int* __restrict__ row,
                                                  const int* __restrict__ rend,
                                                  const int* __restrict__ csr,
                                                  const float* __restrict__ z,
                                                  float* __restrict__ agg) {
    int n = blockIdx.x * 8 + (threadIdx.x >> 5);
    int f = threadIdx.x & 31;
    int j = row[n], e = rend[n];
    float a0 = 0.f, a1 = 0.f, a2 = 0.f, a3 = 0.f;
    for (; j + 3 < e; j += 4) {
        int i0 = csr[j], i1 = csr[j + 1], i2 = csr[j + 2], i3 = csr[j + 3];
        a0 += z[(size_t)i0 * 32 + f];
        a1 += z[(size_t)i1 * 32 + f];
        a2 += z[(size_t)i2 * 32 + f];
        a3 += z[(size_t)i3 * 32 + f];
    }
    for (; j < e; j++) a0 += z[(size_t)csr[j] * 32 + f];
    agg[(size_t)n * 32 + f] = (a0 + a1) + (a2 + a3);
}

__global__ __launch_bounds__(256) void k_gather64(const int* __restrict__ row,
                                                  const int* __restrict__ rend,
                                                  const int* __restrict__ csr,
                                                  const float* __restrict__ z,
                                                  float* __restrict__ agg) {
    int n = blockIdx.x * 4 + (threadIdx.x >> 6);
    int f = threadIdx.x & 63;
    int j = row[n], e = rend[n];
    float a0 = 0.f, a1 = 0.f, a2 = 0.f, a3 = 0.f;
    for (; j + 3 < e; j += 4) {
        int i0 = csr[j], i1 = csr[j + 1], i2 = csr[j + 2], i3 = csr[j + 3];
        a0 += z[(size_t)i0 * 64 + f];
        a1 += z[(size_t)i1 * 64 + f];
        a2 += z[(size_t)i2 * 64 + f];
        a3 += z[(size_t)i3 * 64 + f];
    }
    for (; j < e; j++) a0 += z[(size_t)csr[j] * 64 + f];
    agg[(size_t)n * 64 + f] = (a0 + a1) + (a2 + a3);
}

// ================================================================ z1 = x @ W1
__global__ __launch_bounds__(256) void k_lin1(const float* __restrict__ x,
                                              const float* __restrict__ W1,
                                              float* __restrict__ z1) {
    __shared__ float Ws[128 * 32];
    __shared__ float xs[32][129];
    for (int i = threadIdx.x; i < 1024; i += 256) {
        float4 w = ((const float4*)W1)[i];
        float* d = &Ws[i * 4];
        d[0] = w.x; d[1] = w.y; d[2] = w.z; d[3] = w.w;
    }
    int n_loc = threadIdx.x >> 3;
    int j0    = (threadIdx.x & 7) * 4;
    for (int base = blockIdx.x * 32; base < NN; base += gridDim.x * 32) {
        __syncthreads();
        for (int t = threadIdx.x; t < 1024; t += 256) {
            int n = t >> 5, c = t & 31;
            float4 v = ((const float4*)(x + (size_t)(base + n) * 128))[c];
            float* d = &xs[n][c * 4];
            d[0] = v.x; d[1] = v.y; d[2] = v.z; d[3] = v.w;
        }
        __syncthreads();
        float a0 = 0.f, a1 = 0.f, a2 = 0.f, a3 = 0.f;
        #pragma unroll 8
        for (int k = 0; k < 128; k++) {
            float xv = xs[n_loc][k];
            float4 w = *(const float4*)&Ws[k * 32 + j0];
            a0 = fmaf(xv, w.x, a0); a1 = fmaf(xv, w.y, a1);
            a2 = fmaf(xv, w.z, a2); a3 = fmaf(xv, w.w, a3);
        }
        *(float4*)&z1[(size_t)(base + n_loc) * 32 + j0] = make_float4(a0, a1, a2, a3);
    }
}

// --------------- fused: t = relu(z1+agg1+b1); h = relu(t@W2+b2); z2 = h@W3
__global__ __launch_bounds__(256) void k_mid(const float* __restrict__ z1,
                                             const float* __restrict__ agg1,
                                             const float* __restrict__ b1,
                                             const float* __restrict__ W2,
                                             const float* __restrict__ b2,
                                             const float* __restrict__ W3,
                                             float* __restrict__ z2) {
    __shared__ float W2s[32 * 64];
    __shared__ float W3s[64 * 64];
    __shared__ float ts[32][33];
    __shared__ float hs[32 * 68];
    __shared__ float b1s[32], b2s[64];
    for (int i = threadIdx.x; i < 512; i += 256) {
        float4 w = ((const float4*)W2)[i];
        float* d = &W2s[i * 4];
        d[0] = w.x; d[1] = w.y; d[2] = w.z; d[3] = w.w;
    }
    for (int i = threadIdx.x; i < 1024; i += 256) {
        float4 w = ((const float4*)W3)[i];
        float* d = &W3s[i * 4];
        d[0] = w.x; d[1] = w.y; d[2] = w.z; d[3] = w.w;
    }
    if (threadIdx.x < 32) b1s[threadIdx.x] = b1[threadIdx.x];
    if (threadIdx.x >= 64 && threadIdx.x < 128) b2s[threadIdx.x - 64] = b2[threadIdx.x - 64];
    int n2 = threadIdx.x >> 4;
    int j0 = (threadIdx.x & 15) * 4;
    int na = 2 * n2, nb = 2 * n2 + 1;
    for (int base = blockIdx.x * 32; base < NN; base += gridDim.x * 32) {
        __syncthreads();
        #pragma unroll
        for (int r = 0; r < 4; r++) {
            int idx = threadIdx.x + 256 * r;
            int n = idx >> 5, f = idx & 31;
            ts[n][f] = fmaxf(z1[(size_t)base * 32 + idx] + agg1[(size_t)base * 32 + idx] + b1s[f], 0.f);
        }
        __syncthreads();
        {
            float a00=0,a01=0,a02=0,a03=0,a10=0,a11=0,a12=0,a13=0;
            #pragma unroll 8
            for (int k = 0; k < 32; k++) {
                float t0 = ts[na][k], t1 = ts[nb][k];
                float4 w = *(const float4*)&W2s[k * 64 + j0];
                a00=fmaf(t0,w.x,a00); a01=fmaf(t0,w.y,a01); a02=fmaf(t0,w.z,a02); a03=fmaf(t0,w.w,a03);
                a10=fmaf(t1,w.x,a10); a11=fmaf(t1,w.y,a11); a12=fmaf(t1,w.z,a12); a13=fmaf(t1,w.w,a13);
            }
            *(float4*)&hs[na * 68 + j0] = make_float4(fmaxf(a00+b2s[j0],0.f), fmaxf(a01+b2s[j0+1],0.f),
                                                      fmaxf(a02+b2s[j0+2],0.f), fmaxf(a03+b2s[j0+3],0.f));
            *(float4*)&hs[nb * 68 + j0] = make_float4(fmaxf(a10+b2s[j0],0.f), fmaxf(a11+b2s[j0+1],0.f),
                                                      fmaxf(a12+b2s[j0+2],0.f), fmaxf(a13+b2s[j0+3],0.f));
        }
        __syncthreads();
        {
            float a00=0,a01=0,a02=0,a03=0,a10=0,a11=0,a12=0,a13=0;
            #pragma unroll 8
            for (int k = 0; k < 64; k++) {
                float h0 = hs[na * 68 + k], h1 = hs[nb * 68 + k];
                float4 w = *(const float4*)&W3s[k * 64 + j0];
                a00=fmaf(h0,w.x,a00); a01=fmaf(h0,w.y,a01); a02=fmaf(h0,w.z,a02); a03=fmaf(h0,w.w,a03);
                a10=fmaf(h1,w.x,a10); a11=fmaf(h1,w.y,a11); a12=fmaf(h1,w.z,a12); a13=fmaf(h1,w.w,a13);
            }
            *(float4*)&z2[(size_t)(base + na) * 64 + j0] = make_float4(a00,a01,a02,a03);
            *(float4*)&z2[(size_t)(base + nb) * 64 + j0] = make_float4(a10,a11,a12,a13);
        }
    }
}

// --------- final: u = relu(z2+agg2+b3); out = relu(u@W4+b4) -> f32 + pooled
__global__ __launch_bounds__(256) void k_final(const float* __restrict__ z2,
                                               const float* __restrict__ agg2,
                                               const float* __restrict__ b3,
                                               const float* __restrict__ W4,
                                               const float* __restrict__ b4,
                                               float* __restrict__ out,
                                               float* __restrict__ gpool) {
    __shared__ float W4s[64 * 64];
    __shared__ float us[32 * 68];
    __shared__ float b3s[64], b4s[64], pool[64];
    for (int i = threadIdx.x; i < 1024; i += 256) {
        float4 w = ((const float4*)W4)[i];
        float* d = &W4s[i * 4];
        d[0] = w.x; d[1] = w.y; d[2] = w.z; d[3] = w.w;
    }
    if (threadIdx.x < 64) { b3s[threadIdx.x] = b3[threadIdx.x]; pool[threadIdx.x] = 0.f; }
    if (threadIdx.x >= 64 && threadIdx.x < 128) b4s[threadIdx.x - 64] = b4[threadIdx.x - 64];
    int n2 = threadIdx.x >> 4;
    int j0 = (threadIdx.x & 15) * 4;
    int na = 2 * n2, nb = 2 * n2 + 1;
    float p0 = 0.f, p1 = 0.f, p2 = 0.f, p3 = 0.f;
    for (int base = blockIdx.x * 32; base < NN; base += gridDim.x * 32) {
        __syncthreads();
        #pragma unroll
        for (int r = 0; r < 8; r++) {
            int idx = threadIdx.x + 256 * r;
            int n = idx >> 6, f = idx & 63;
            us[n * 68 + f] = fmaxf(z2[(size_t)base * 64 + idx] + agg2[(size_t)base * 64 + idx] + b3s[f], 0.f);
        }
        __syncthreads();
        float a00=0,a01=0,a02=0,a03=0,a10=0,a11=0,a12=0,a13=0;
        #pragma unroll 8
        for (int k = 0; k < 64; k++) {
            float u0 = us[na * 68 + k], u1 = us[nb * 68 + k];
            float4 w = *(const float4*)&W4s[k * 64 + j0];
            a00=fmaf(u0,w.x,a00); a01=fmaf(u0,w.y,a01); a02=fmaf(u0,w.z,a02); a03=fmaf(u0,w.w,a03);
            a10=fmaf(u1,w.x,a10); a11=fmaf(u1,w.y,a11); a12=fmaf(u1,w.z,a12); a13=fmaf(u1,w.w,a13);
        }
        float v00=fmaxf(a00+b4s[j0],0.f), v01=fmaxf(a01+b4s[j0+1],0.f);
        float v02=fmaxf(a02+b4s[j0+2],0.f), v03=fmaxf(a03+b4s[j0+3],0.f);
        float v10=fmaxf(a10+b4s[j0],0.f), v11=fmaxf(a11+b4s[j0+1],0.f);
        float v12=fmaxf(a12+b4s[j0+2],0.f), v13=fmaxf(a13+b4s[j0+3],0.f);
        *(float4*)&out[(size_t)(base + na) * 64 + j0] = make_float4(v00, v01, v02, v03);
        *(float4*)&out[(size_t)(base + nb) * 64 + j0] = make_float4(v10, v11, v12, v13);
        p0 += v00 + v10; p1 += v01 + v11; p2 += v02 + v12; p3 += v03 + v13;
    }
    __syncthreads();
    atomicAdd(&pool[j0 + 0], p0);
    atomicAdd(&pool[j0 + 1], p1);
    atomicAdd(&pool[j0 + 2], p2);
    atomicAdd(&pool[j0 + 3], p3);
    __syncthreads();
    if (threadIdx.x < 64) unsafeAtomicAdd(&gpool[threadIdx.x], pool[threadIdx.x]);
}

__global__ void k_pool(const float* __restrict__ gpool, float* __restrict__ out) {
    int t = threadIdx.x;
    if (t < 64) out[(size_t)NN * 64 + t] = gpool[t] * (1.0f / NN);
}

extern "C" void kernel_launch(void* const* d_in, const int* in_sizes, int n_in,
                              void* d_out, int out_size, void* d_ws, size_t ws_size,
                              hipStream_t stream) {
    const float* x  = (const float*)d_in[0];
    const int*   ei = (const int*)d_in[1];
    const float* W1 = (const float*)d_in[3];
    const float* b1 = (const float*)d_in[4];
    const float* W2 = (const float*)d_in[5];
    const float* b2 = (const float*)d_in[6];
    const float* W3 = (const float*)d_in[7];
    const float* b3 = (const float*)d_in[8];
    const float* W4 = (const float*)d_in[9];
    const float* b4 = (const float*)d_in[10];
    float* out = (float*)d_out;

    // ws layout (4B units):
    //   tstart[NLB*NB] tcnt[NLB*NB] btot[NB] gpool[64] row[NN] rend[NN] csr[NE]
    //   f32: z1[NN*32] agg1[NN*32] z2[NN*64]
    //   pairs[NE] (int2) ALIASES z2 (dead before k_mid writes z2)
    //   agg2 ALIASES z1+agg1 (dead after k_mid).   total ~58.6 MB
    int*   ip     = (int*)d_ws;
    int*   tstart = ip;                       // 25088
    int*   tcnt   = ip + NLB * NB;            // 25088
    int*   btot   = ip + 2 * NLB * NB;        // 98
    float* gpool  = (float*)(ip + 2 * NLB * NB + 98);  // 64
    int*   row    = ip + 2 * NLB * NB + 192;  // NN (aligned start)
    int*   rend   = row + NN;
    int*   csr    = rend + NN;                // NE
    float* fp     = (float*)(csr + NE + 32);  // align
    float* z1     = fp;                       // NN*32
    float* agg1   = fp + (size_t)NN * 32;     // NN*32
    float* agg2   = fp;                       // alias z1+agg1
    float* z2     = fp + (size_t)NN * 64;     // NN*64
    int2*  pairs  = (int2*)z2;                // alias z2 (NE int2 = NN*32 f32)
    const int* src = ei;
    const int* dst = ei + NE;

    hipMemsetAsync(btot, 0, (98 + 64) * sizeof(int), stream);  // btot + gpool
    k_lsort<<<NLB, 256, 0, stream>>>(src, dst, pairs, tstart, tcnt, btot);
    k_build<<<NB, 256, 0, stream>>>(pairs, tstart, tcnt, btot, csr, row, rend);
    k_lin1<<<1024, 256, 0, stream>>>(x, W1, z1);
    k_gather32<<<NN / 8, 256, 0, stream>>>(row, rend, csr, z1, agg1);
    k_mid<<<1024, 256, 0, stream>>>(z1, agg1, b1, W2, b2, W3, z2);
    k_gather64<<<NN / 4, 256, 0, stream>>>(row, rend, csr, z2, agg2);
    k_final<<<1024, 256, 0, stream>>>(z2, agg2, b3, W4, b4, out, gpool);
    k_pool<<<1, 64, 0, stream>>>(gpool, out);
}